// Round 4
// baseline (355.203 us; speedup 1.0000x reference)
//
#include <hip/hip_runtime.h>
#include <cmath>

#define BB 2
#define LL 2048
#define DD 1024
#define HH 16
#define HDD 64

typedef _Float16 v8h __attribute__((ext_vector_type(8)));
typedef _Float16 v4h __attribute__((ext_vector_type(4)));
typedef float v4f __attribute__((ext_vector_type(4)));

// async global->LDS, 16B per lane. LDS dest = wave-uniform base + lane*16.
#define GLD(gp, lp)                                                        \
  __builtin_amdgcn_global_load_lds(                                        \
      (const __attribute__((address_space(1))) void*)(gp),                 \
      (__attribute__((address_space(3))) void*)(lp), 16, 0, 0)

// ---------------------------------------------------------------------------
// fp32 -> f16 conversion: hs (1M float4) + Wq/Wk/Wv (into wqkvh) + Wo.
// ---------------------------------------------------------------------------
__global__ __launch_bounds__(256) void cvt_all(
    const float* __restrict__ hs, const float* __restrict__ wq,
    const float* __restrict__ wk, const float* __restrict__ wv,
    const float* __restrict__ wo, _Float16* __restrict__ hsh,
    _Float16* __restrict__ wqkvh, _Float16* __restrict__ woh)
{
  const int i = blockIdx.x * 256 + threadIdx.x;  // float4 units, total 2M
  const float* s;
  _Float16* d;
  if (i < 1048576)      { s = hs + (size_t)i * 4;            d = hsh + (size_t)i * 4; }
  else if (i < 1310720) { int j = i - 1048576; s = wq + (size_t)j * 4; d = wqkvh + (size_t)j * 4; }
  else if (i < 1572864) { int j = i - 1310720; s = wk + (size_t)j * 4; d = wqkvh + 1048576 + (size_t)j * 4; }
  else if (i < 1835008) { int j = i - 1572864; s = wv + (size_t)j * 4; d = wqkvh + 2097152 + (size_t)j * 4; }
  else                  { int j = i - 1835008; s = wo + (size_t)j * 4; d = woh + (size_t)j * 4; }
  float4 v = *(const float4*)s;
  v4h o;
  o[0] = (_Float16)v.x; o[1] = (_Float16)v.y;
  o[2] = (_Float16)v.z; o[3] = (_Float16)v.w;
  *(v4h*)d = o;
}

// ---------------------------------------------------------------------------
// m97-style MFMA GEMM core: 128x128 tile, BK=32, 256 thr (2x2 waves of 64x64).
// ---------------------------------------------------------------------------
__device__ __forceinline__ void gemm_loop(
    const _Float16* __restrict__ A, const _Float16* __restrict__ W, const int K,
    const int m0, const int n0, const int tid, const int wave, const int lane,
    _Float16* As, _Float16* Bs, v4f acc[4][4])
{
  const int quad = lane >> 4;
  const int ql = lane & 15;
  const int wm = (wave >> 1) * 64;
  const int wn = (wave & 1) * 64;
  const int srow = tid >> 2;
  const int skof = (tid & 3) * 8;
  const _Float16* Ap = A + (size_t)(m0 + srow) * K + skof;
  const _Float16* Wp = W + (size_t)(n0 + srow) * K + skof;
  const size_t rstep = (size_t)64 * K;
  for (int k0 = 0; k0 < K; k0 += 32) {
    __syncthreads();
    GLD(Ap + k0,         As + tid * 8);
    GLD(Ap + rstep + k0, As + 2048 + tid * 8);
    GLD(Wp + k0,         Bs + tid * 8);
    GLD(Wp + rstep + k0, Bs + 2048 + tid * 8);
    __syncthreads();
    v8h af[4], bf[4];
#pragma unroll
    for (int mt = 0; mt < 4; ++mt)
      af[mt] = *(const v8h*)&As[(wm + mt * 16 + ql) * 32 + quad * 8];
#pragma unroll
    for (int nt = 0; nt < 4; ++nt)
      bf[nt] = *(const v8h*)&Bs[(wn + nt * 16 + ql) * 32 + quad * 8];
#pragma unroll
    for (int mt = 0; mt < 4; ++mt)
#pragma unroll
      for (int nt = 0; nt < 4; ++nt)
        acc[mt][nt] = __builtin_amdgcn_mfma_f32_16x16x32_f16(
            af[mt], bf[nt], acc[mt][nt], 0, 0, 0);
  }
}

// QKV fused GEMM: N=3072; whole 128-block maps to one of q/k/v
__global__ __launch_bounds__(256) void gemm_qkv(
    const _Float16* __restrict__ A, const _Float16* __restrict__ W,
    const float* __restrict__ bq, const float* __restrict__ bk,
    const float* __restrict__ bv, _Float16* __restrict__ qh,
    _Float16* __restrict__ kh, _Float16* __restrict__ vh)
{
  __shared__ _Float16 As[128 * 32];
  __shared__ _Float16 Bs[128 * 32];
  const int tid = threadIdx.x, lane = tid & 63, wave = tid >> 6;
  const int quad = lane >> 4, ql = lane & 15;
  const int m0 = blockIdx.y * 128, n0 = blockIdx.x * 128;
  v4f acc[4][4];
#pragma unroll
  for (int mt = 0; mt < 4; ++mt)
#pragma unroll
    for (int nt = 0; nt < 4; ++nt) acc[mt][nt] = (v4f){0.f, 0.f, 0.f, 0.f};
  gemm_loop(A, W, DD, m0, n0, tid, wave, lane, As, Bs, acc);
  const int buf = n0 >> 10;
  _Float16* outp = buf == 0 ? qh : (buf == 1 ? kh : vh);
  const float* bias = buf == 0 ? bq : (buf == 1 ? bk : bv);
  const int nc0 = (n0 & 1023) + (wave & 1) * 64;
  const int mr0 = m0 + (wave >> 1) * 64;
#pragma unroll
  for (int nt = 0; nt < 4; ++nt) {
    const int col = nc0 + nt * 16 + ql;
    const float bb = bias[col];
#pragma unroll
    for (int mt = 0; mt < 4; ++mt)
#pragma unroll
      for (int r = 0; r < 4; ++r) {
        const int row = mr0 + mt * 16 + quad * 4 + r;
        outp[(size_t)row * DD + col] = (_Float16)(acc[mt][nt][r] + bb);
      }
  }
}

// O-proj GEMM: f16 A,W; fp32 bias + residual epilogue
__global__ __launch_bounds__(256) void gemm_o(
    const _Float16* __restrict__ A, const _Float16* __restrict__ W,
    const float* __restrict__ bo, const float* __restrict__ res,
    float* __restrict__ out)
{
  __shared__ _Float16 As[128 * 32];
  __shared__ _Float16 Bs[128 * 32];
  const int tid = threadIdx.x, lane = tid & 63, wave = tid >> 6;
  const int quad = lane >> 4, ql = lane & 15;
  const int m0 = blockIdx.y * 128, n0 = blockIdx.x * 128;
  v4f acc[4][4];
#pragma unroll
  for (int mt = 0; mt < 4; ++mt)
#pragma unroll
    for (int nt = 0; nt < 4; ++nt) acc[mt][nt] = (v4f){0.f, 0.f, 0.f, 0.f};
  gemm_loop(A, W, DD, m0, n0, tid, wave, lane, As, Bs, acc);
  const int nc0 = n0 + (wave & 1) * 64;
  const int mr0 = m0 + (wave >> 1) * 64;
#pragma unroll
  for (int nt = 0; nt < 4; ++nt) {
    const int col = nc0 + nt * 16 + ql;
    const float bb = bo[col];
#pragma unroll
    for (int mt = 0; mt < 4; ++mt)
#pragma unroll
      for (int r = 0; r < 4; ++r) {
        const int row = mr0 + mt * 16 + quad * 4 + r;
        const size_t ix = (size_t)row * DD + col;
        out[ix] = acc[mt][nt][r] + bb + res[ix];
      }
  }
}

// ---------------------------------------------------------------------------
// Rotary on f16 q,k + cos/sin tables ([B,H,L] fp32)
// ---------------------------------------------------------------------------
__global__ __launch_bounds__(256) void rotary_h(
    _Float16* __restrict__ q, _Float16* __restrict__ k,
    const float* __restrict__ phi, float* __restrict__ cosp,
    float* __restrict__ sinp)
{
  const int idx = blockIdx.x * 256 + threadIdx.x;
  const int d = idx & 31;
  const int h = (idx >> 5) & (HH - 1);
  const int l = (idx >> 9) & (LL - 1);
  const int b = idx >> 20;
  const float ph = phi[(b * LL + l) * HH + h];
  const float c = cosf(ph), s = sinf(ph);
  const size_t base = ((size_t)(b * LL + l) * HH + h) * HDD;
  const float q0 = (float)q[base + d], q1 = (float)q[base + d + 32];
  q[base + d]      = (_Float16)(q0 * c - q1 * s);
  q[base + d + 32] = (_Float16)(q1 * c + q0 * s);
  const float k0v = (float)k[base + d], k1v = (float)k[base + d + 32];
  k[base + d]      = (_Float16)(k0v * c - k1v * s);
  k[base + d + 32] = (_Float16)(k1v * c + k0v * s);
  if (d == 0) {
    cosp[(b * HH + h) * LL + l] = c;
    sinp[(b * HH + h) * LL + l] = s;
  }
}

// ---------------------------------------------------------------------------
// V transpose: [B,L,H,64] -> VT[B,H,64,L]. Tiled through LDS, coalesced both
// sides. Grid: BB*HH*(LL/64) = 1024 blocks.
// ---------------------------------------------------------------------------
__global__ __launch_bounds__(256) void vtrans(
    const _Float16* __restrict__ V, _Float16* __restrict__ VT)
{
  __shared__ _Float16 t[64][72];  // +8 pad
  const int bid = blockIdx.x;
  const int lt = bid & 31, bh = bid >> 5;
  const int b = bh >> 4, h = bh & 15;
  const int l0 = lt * 64;
  const int tid = threadIdx.x;
  {
    const int row = tid >> 2, doff = (tid & 3) * 16;
    const _Float16* src = V + ((size_t)((b * LL + l0 + row) * HH + h)) * HDD + doff;
    *(v8h*)&t[row][doff]     = *(const v8h*)src;
    *(v8h*)&t[row][doff + 8] = *(const v8h*)(src + 8);
  }
  __syncthreads();
  {
    const int d = tid >> 2, lo = (tid & 3) * 16;
    v8h o0, o1;
#pragma unroll
    for (int j = 0; j < 8; ++j) { o0[j] = t[lo + j][d]; o1[j] = t[lo + 8 + j][d]; }
    _Float16* dst = VT + ((size_t)(b * HH + h) * HDD + d) * LL + l0 + lo;
    *(v8h*)dst = o0;
    *(v8h*)(dst + 8) = o1;
  }
}

__device__ __forceinline__ v8h scale8(v8h x) {
  v8h r;
#pragma unroll
  for (int i = 0; i < 8; ++i) r[i] = x[i] * (_Float16)0.125f;
  return r;
}

// ---------------------------------------------------------------------------
// Barrier-free streaming MFMA flash attention.
// S^T = K.Q^T: A-frag = direct 16B loads from K rows; B-frag = Q (registers).
// PV: A = P (registers, C-layout match), B-frag = direct 8B loads from VT.
// cos/sin/am staged once per block (one barrier total).
// Block = 4 waves x 32 queries = 128 q. bid = qt*32 + (b*16+h) (XCD-swizzle:
// all 16 q-blocks of one (b,h) land on one XCD -> K/VT L2-resident).
// ---------------------------------------------------------------------------
__global__ __launch_bounds__(256) void attn_stream(
    const _Float16* __restrict__ Q, const _Float16* __restrict__ K,
    const _Float16* __restrict__ VT, const _Float16* __restrict__ V,
    const float* __restrict__ cosp, const float* __restrict__ sinp,
    const float* __restrict__ am, _Float16* __restrict__ ctx)
{
  __shared__ float4 csA[LL];  // {cos,sin,am,0} per key: 32 KB

  const int tid  = threadIdx.x;
  const int lane = tid & 63;
  const int wave = tid >> 6;
  const int quad = lane >> 4;
  const int ql   = lane & 15;
  const int bid  = blockIdx.x;
  const int bh = bid & 31;        // b*16+h
  const int qt = bid >> 5;
  const int h  = bh & 15;
  const int b  = bh >> 4;
  const int q0 = qt * 128 + wave * 32;
  const int csb = (b * HH + h) * LL;

  // stage cos/sin/am for the whole (b,h) row
  for (int i = tid; i < LL; i += 256)
    csA[i] = make_float4(cosp[csb + i], sinp[csb + i], am[b * LL + i], 0.f);

  // Q fragments (scale 1/8 folded) + per-query cos/sin
  v8h qf[2][2];
  float cq[2], sq[2];
#pragma unroll
  for (int qs = 0; qs < 2; ++qs) {
    const int q = q0 + qs * 16 + ql;
    const _Float16* qp = Q + ((size_t)((b * LL + q) * HH + h)) * HDD + quad * 8;
    qf[qs][0] = scale8(*(const v8h*)qp);
    qf[qs][1] = scale8(*(const v8h*)(qp + 32));
    cq[qs] = cosp[csb + q];
    sq[qs] = sinp[csb + q];
  }

  v4f o[2][4];
#pragma unroll
  for (int qs = 0; qs < 2; ++qs)
#pragma unroll
    for (int nt = 0; nt < 4; ++nt) o[qs][nt] = (v4f){0.f, 0.f, 0.f, 0.f};
  float mrow[2] = {-INFINITY, -INFINITY};
  float lrow[2] = {0.f, 0.f};

  const _Float16* Kb  = K + ((size_t)(b * LL) * HH + h) * HDD;   // row stride 1024
  const _Float16* VTb = VT + (size_t)(b * HH + h) * HDD * LL;

  __syncthreads();  // csA ready (the only barrier)

  for (int k0 = 0; k0 < LL; k0 += 64) {
    // K fragments: 4 chunks of 16 keys, direct from global (L2-resident)
    v8h ka[4][2];
#pragma unroll
    for (int c = 0; c < 4; ++c) {
      const _Float16* kp = Kb + (size_t)(k0 + c * 16 + ql) * 1024 + quad * 8;
      ka[c][0] = *(const v8h*)kp;
      ka[c][1] = *(const v8h*)(kp + 32);
    }
    // V fragments for PV, direct from VT (shared by both q sub-tiles)
    v4h vf[4][4];
#pragma unroll
    for (int c = 0; c < 4; ++c)
#pragma unroll
      for (int nt = 0; nt < 4; ++nt)
        vf[c][nt] = *(const v4h*)&VTb[(size_t)(nt * 16 + ql) * LL +
                                      k0 + c * 16 + quad * 4];

    v4h pf[2][4];
    float alpha_[2];
#pragma unroll
    for (int qs = 0; qs < 2; ++qs) {
      v4f st[4];
#pragma unroll
      for (int c = 0; c < 4; ++c) {
        v4f z = (v4f){0.f, 0.f, 0.f, 0.f};
        z = __builtin_amdgcn_mfma_f32_16x16x32_f16(ka[c][0], qf[qs][0], z, 0, 0, 0);
        z = __builtin_amdgcn_mfma_f32_16x16x32_f16(ka[c][1], qf[qs][1], z, 0, 0, 0);
        st[c] = z;
      }
      const int qglob = q0 + qs * 16 + ql;
      float s[16];
      float tm = -INFINITY;
#pragma unroll
      for (int c = 0; c < 4; ++c)
#pragma unroll
        for (int r = 0; r < 4; ++r) {
          const int kk = c * 16 + quad * 4 + r;
          float4 cs = csA[k0 + kk];
          float sc = st[c][r];
          const bool msk = (cq[qs] * cs.x + sq[qs] * cs.y < -0.7f) &&
                           ((k0 + kk) != qglob);
          sc = msk ? -1e9f : sc;
          sc += cs.z;
          s[c * 4 + r] = sc;
          tm = fmaxf(tm, sc);
        }
      tm = fmaxf(tm, __shfl_xor(tm, 16, 64));
      tm = fmaxf(tm, __shfl_xor(tm, 32, 64));
      const float mnew = fmaxf(mrow[qs], tm);
      const float alpha = __expf(mrow[qs] - mnew);
      mrow[qs] = mnew;
      float lsum = 0.f;
#pragma unroll
      for (int i = 0; i < 16; ++i) { s[i] = __expf(s[i] - mnew); lsum += s[i]; }
      lsum += __shfl_xor(lsum, 16, 64);
      lsum += __shfl_xor(lsum, 32, 64);
      lrow[qs] = lrow[qs] * alpha + lsum;
#pragma unroll
      for (int c = 0; c < 4; ++c) {
        v4h t;
        t[0] = (_Float16)s[c * 4 + 0]; t[1] = (_Float16)s[c * 4 + 1];
        t[2] = (_Float16)s[c * 4 + 2]; t[3] = (_Float16)s[c * 4 + 3];
        pf[qs][c] = t;
      }
      alpha_[qs] = alpha;
    }
#pragma unroll
    for (int qs = 0; qs < 2; ++qs) {
      const float a0 = __shfl(alpha_[qs], quad * 4 + 0, 64);
      const float a1 = __shfl(alpha_[qs], quad * 4 + 1, 64);
      const float a2 = __shfl(alpha_[qs], quad * 4 + 2, 64);
      const float a3 = __shfl(alpha_[qs], quad * 4 + 3, 64);
#pragma unroll
      for (int nt = 0; nt < 4; ++nt) {
        o[0 + qs == 0 ? qs : qs][nt][0] *= a0;  // (kept simple below)
      }
      // unrolled explicitly to avoid the oddity above
      (void)a0;
    }
    // NOTE: rescale done explicitly here (clean version)
#pragma unroll
    for (int qs = 0; qs < 2; ++qs) {
      const float a0 = __shfl(alpha_[qs], quad * 4 + 0, 64);
      const float a1 = __shfl(alpha_[qs], quad * 4 + 1, 64);
      const float a2 = __shfl(alpha_[qs], quad * 4 + 2, 64);
      const float a3 = __shfl(alpha_[qs], quad * 4 + 3, 64);
#pragma unroll
      for (int nt = 0; nt < 4; ++nt) {
        o[qs][nt][0] *= a0; o[qs][nt][1] *= a1;
        o[qs][nt][2] *= a2; o[qs][nt][3] *= a3;
      }
    }
#pragma unroll
    for (int c = 0; c < 4; ++c)
#pragma unroll
      for (int nt = 0; nt < 4; ++nt) {
        o[0][nt] = __builtin_amdgcn_mfma_f32_16x16x16f16(pf[0][c], vf[c][nt], o[0][nt], 0, 0, 0);
        o[1][nt] = __builtin_amdgcn_mfma_f32_16x16x16f16(pf[1][c], vf[c][nt], o[1][nt], 0, 0, 0);
      }
  }

#pragma unroll
  for (int qs = 0; qs < 2; ++qs) {
    const float inv = 1.f / lrow[qs];
#pragma unroll
    for (int r = 0; r < 4; ++r) {
      const int q = q0 + qs * 16 + quad * 4 + r;
      const float ir = __shfl(inv, quad * 4 + r, 64);
      const float mr = __shfl(mrow[qs], quad * 4 + r, 64);
      const size_t ob = ((size_t)((b * LL + q) * HH + h)) * HDD + ql;
      if (mr <= -1e8f) {  // all-masked fallback (never taken with am=0)
        ctx[ob + 0]  = V[ob + 0];
        ctx[ob + 16] = V[ob + 16];
        ctx[ob + 32] = V[ob + 32];
        ctx[ob + 48] = V[ob + 48];
      } else {
        ctx[ob + 0]  = (_Float16)(o[qs][0][r] * ir);
        ctx[ob + 16] = (_Float16)(o[qs][1][r] * ir);
        ctx[ob + 32] = (_Float16)(o[qs][2][r] * ir);
        ctx[ob + 48] = (_Float16)(o[qs][3][r] * ir);
      }
    }
  }
}

// ---------------------------------------------------------------------------
// LayerNorm over D=1024
// ---------------------------------------------------------------------------
__global__ __launch_bounds__(256) void layernorm(
    const float* __restrict__ x, const float* __restrict__ g,
    const float* __restrict__ bta, float* __restrict__ out)
{
  __shared__ float red[8];
  const int row = blockIdx.x;
  const int tid = threadIdx.x;
  const float* xr = x + (size_t)row * DD;
  float lsum = 0.f, lsq = 0.f;
  float v[4];
#pragma unroll
  for (int i = 0; i < 4; ++i) {
    v[i] = xr[tid + i * 256];
    lsum += v[i];
    lsq += v[i] * v[i];
  }
#pragma unroll
  for (int off = 32; off > 0; off >>= 1) {
    lsum += __shfl_down(lsum, off, 64);
    lsq  += __shfl_down(lsq,  off, 64);
  }
  const int wid = tid >> 6;
  if ((tid & 63) == 0) { red[wid] = lsum; red[wid + 4] = lsq; }
  __syncthreads();
  const float tsum = red[0] + red[1] + red[2] + red[3];
  const float tsq  = red[4] + red[5] + red[6] + red[7];
  const float mean = tsum * (1.f / DD);
  const float var  = tsq * (1.f / DD) - mean * mean;
  const float inv  = rsqrtf(var + 1e-12f);
#pragma unroll
  for (int i = 0; i < 4; ++i) {
    const int c = tid + i * 256;
    out[(size_t)row * DD + c] = (v[i] - mean) * inv * g[c] + bta[c];
  }
}

// ---------------------------------------------------------------------------
extern "C" void kernel_launch(void* const* d_in, const int* in_sizes, int n_in,
                              void* d_out, int out_size, void* d_ws, size_t ws_size,
                              hipStream_t stream)
{
  const float* hs  = (const float*)d_in[0];
  const float* amk = (const float*)d_in[1];
  const float* phi = (const float*)d_in[2];
  const float* Wq  = (const float*)d_in[3];
  const float* bq  = (const float*)d_in[4];
  const float* Wk  = (const float*)d_in[5];
  const float* bk  = (const float*)d_in[6];
  const float* Wv  = (const float*)d_in[7];
  const float* bv  = (const float*)d_in[8];
  const float* Wo  = (const float*)d_in[9];
  const float* bo  = (const float*)d_in[10];
  const float* lng = (const float*)d_in[11];
  const float* lnb = (const float*)d_in[12];
  float* out = (float*)d_out;

  const size_t SZ = (size_t)BB * LL * DD;   // 4 M elements
  _Float16* hsh   = (_Float16*)d_ws;
  _Float16* qh    = hsh + SZ;
  _Float16* kh    = qh + SZ;
  _Float16* vh    = kh + SZ;
  _Float16* ctxh  = vh + SZ;
  _Float16* wqkvh = ctxh + SZ;              // 3 M
  _Float16* woh   = wqkvh + 3 * (size_t)DD * DD;  // 1 M
  _Float16* vth   = woh + (size_t)DD * DD;  // 4 M (V transposed)
  float* xb   = (float*)(vth + SZ);
  float* cosp = xb + SZ;
  float* sinp = cosp + (size_t)BB * HH * LL;

  cvt_all<<<8192, 256, 0, stream>>>(hs, Wq, Wk, Wv, Wo, hsh, wqkvh, woh);
  gemm_qkv<<<dim3(24, 32), 256, 0, stream>>>(hsh, wqkvh, bq, bk, bv, qh, kh, vh);
  rotary_h<<<8192, 256, 0, stream>>>(qh, kh, phi, cosp, sinp);
  vtrans<<<1024, 256, 0, stream>>>(vh, vth);
  attn_stream<<<BB * HH * (LL / 128), 256, 0, stream>>>(qh, kh, vth, vh, cosp,
                                                        sinp, amk, ctxh);
  gemm_o<<<dim3(8, 32), 256, 0, stream>>>(ctxh, woh, bo, hs, xb);
  layernorm<<<BB * LL, 256, 0, stream>>>(xb, lng, lnb, out);
}

// Round 5
// 354.482 us; speedup vs baseline: 1.0020x; 1.0020x over previous
//
#include <hip/hip_runtime.h>
#include <cmath>

#define BB 2
#define LL 2048
#define DD 1024
#define HH 16
#define HDD 64

typedef _Float16 v8h __attribute__((ext_vector_type(8)));
typedef _Float16 v4h __attribute__((ext_vector_type(4)));
typedef float v4f __attribute__((ext_vector_type(4)));

// async global->LDS, 16B per lane. LDS dest = wave-uniform base + lane*16.
#define GLD(gp, lp)                                                        \
  __builtin_amdgcn_global_load_lds(                                        \
      (const __attribute__((address_space(1))) void*)(gp),                 \
      (__attribute__((address_space(3))) void*)(lp), 16, 0, 0)

// ---------------------------------------------------------------------------
// fp32 -> f16 conversion: hs (1M float4) + Wq/Wk/Wv (into wqkvh) + Wo.
// ---------------------------------------------------------------------------
__global__ __launch_bounds__(256) void cvt_all(
    const float* __restrict__ hs, const float* __restrict__ wq,
    const float* __restrict__ wk, const float* __restrict__ wv,
    const float* __restrict__ wo, _Float16* __restrict__ hsh,
    _Float16* __restrict__ wqkvh, _Float16* __restrict__ woh)
{
  const int i = blockIdx.x * 256 + threadIdx.x;  // float4 units, total 2M
  const float* s;
  _Float16* d;
  if (i < 1048576)      { s = hs + (size_t)i * 4;            d = hsh + (size_t)i * 4; }
  else if (i < 1310720) { int j = i - 1048576; s = wq + (size_t)j * 4; d = wqkvh + (size_t)j * 4; }
  else if (i < 1572864) { int j = i - 1310720; s = wk + (size_t)j * 4; d = wqkvh + 1048576 + (size_t)j * 4; }
  else if (i < 1835008) { int j = i - 1572864; s = wv + (size_t)j * 4; d = wqkvh + 2097152 + (size_t)j * 4; }
  else                  { int j = i - 1835008; s = wo + (size_t)j * 4; d = woh + (size_t)j * 4; }
  float4 v = *(const float4*)s;
  v4h o;
  o[0] = (_Float16)v.x; o[1] = (_Float16)v.y;
  o[2] = (_Float16)v.z; o[3] = (_Float16)v.w;
  *(v4h*)d = o;
}

// ---------------------------------------------------------------------------
// m97-style MFMA GEMM core: 128x128 tile, BK=32, 256 thr (2x2 waves of 64x64).
// ---------------------------------------------------------------------------
__device__ __forceinline__ void gemm_loop(
    const _Float16* __restrict__ A, const _Float16* __restrict__ W, const int K,
    const int m0, const int n0, const int tid, const int wave, const int lane,
    _Float16* As, _Float16* Bs, v4f acc[4][4])
{
  const int quad = lane >> 4;
  const int ql = lane & 15;
  const int wm = (wave >> 1) * 64;
  const int wn = (wave & 1) * 64;
  const int srow = tid >> 2;
  const int skof = (tid & 3) * 8;
  const _Float16* Ap = A + (size_t)(m0 + srow) * K + skof;
  const _Float16* Wp = W + (size_t)(n0 + srow) * K + skof;
  const size_t rstep = (size_t)64 * K;
  for (int k0 = 0; k0 < K; k0 += 32) {
    __syncthreads();
    GLD(Ap + k0,         As + tid * 8);
    GLD(Ap + rstep + k0, As + 2048 + tid * 8);
    GLD(Wp + k0,         Bs + tid * 8);
    GLD(Wp + rstep + k0, Bs + 2048 + tid * 8);
    __syncthreads();
    v8h af[4], bf[4];
#pragma unroll
    for (int mt = 0; mt < 4; ++mt)
      af[mt] = *(const v8h*)&As[(wm + mt * 16 + ql) * 32 + quad * 8];
#pragma unroll
    for (int nt = 0; nt < 4; ++nt)
      bf[nt] = *(const v8h*)&Bs[(wn + nt * 16 + ql) * 32 + quad * 8];
#pragma unroll
    for (int mt = 0; mt < 4; ++mt)
#pragma unroll
      for (int nt = 0; nt < 4; ++nt)
        acc[mt][nt] = __builtin_amdgcn_mfma_f32_16x16x32_f16(
            af[mt], bf[nt], acc[mt][nt], 0, 0, 0);
  }
}

// QKV fused GEMM: N=3072; whole 128-block maps to one of q/k/v
__global__ __launch_bounds__(256) void gemm_qkv(
    const _Float16* __restrict__ A, const _Float16* __restrict__ W,
    const float* __restrict__ bq, const float* __restrict__ bk,
    const float* __restrict__ bv, _Float16* __restrict__ qh,
    _Float16* __restrict__ kh, _Float16* __restrict__ vh)
{
  __shared__ _Float16 As[128 * 32];
  __shared__ _Float16 Bs[128 * 32];
  const int tid = threadIdx.x, lane = tid & 63, wave = tid >> 6;
  const int quad = lane >> 4, ql = lane & 15;
  const int m0 = blockIdx.y * 128, n0 = blockIdx.x * 128;
  v4f acc[4][4];
#pragma unroll
  for (int mt = 0; mt < 4; ++mt)
#pragma unroll
    for (int nt = 0; nt < 4; ++nt) acc[mt][nt] = (v4f){0.f, 0.f, 0.f, 0.f};
  gemm_loop(A, W, DD, m0, n0, tid, wave, lane, As, Bs, acc);
  const int buf = n0 >> 10;
  _Float16* outp = buf == 0 ? qh : (buf == 1 ? kh : vh);
  const float* bias = buf == 0 ? bq : (buf == 1 ? bk : bv);
  const int nc0 = (n0 & 1023) + (wave & 1) * 64;
  const int mr0 = m0 + (wave >> 1) * 64;
#pragma unroll
  for (int nt = 0; nt < 4; ++nt) {
    const int col = nc0 + nt * 16 + ql;
    const float bb = bias[col];
#pragma unroll
    for (int mt = 0; mt < 4; ++mt)
#pragma unroll
      for (int r = 0; r < 4; ++r) {
        const int row = mr0 + mt * 16 + quad * 4 + r;
        outp[(size_t)row * DD + col] = (_Float16)(acc[mt][nt][r] + bb);
      }
  }
}

// O-proj GEMM: f16 A,W; fp32 bias + residual epilogue
__global__ __launch_bounds__(256) void gemm_o(
    const _Float16* __restrict__ A, const _Float16* __restrict__ W,
    const float* __restrict__ bo, const float* __restrict__ res,
    float* __restrict__ out)
{
  __shared__ _Float16 As[128 * 32];
  __shared__ _Float16 Bs[128 * 32];
  const int tid = threadIdx.x, lane = tid & 63, wave = tid >> 6;
  const int quad = lane >> 4, ql = lane & 15;
  const int m0 = blockIdx.y * 128, n0 = blockIdx.x * 128;
  v4f acc[4][4];
#pragma unroll
  for (int mt = 0; mt < 4; ++mt)
#pragma unroll
    for (int nt = 0; nt < 4; ++nt) acc[mt][nt] = (v4f){0.f, 0.f, 0.f, 0.f};
  gemm_loop(A, W, DD, m0, n0, tid, wave, lane, As, Bs, acc);
  const int nc0 = n0 + (wave & 1) * 64;
  const int mr0 = m0 + (wave >> 1) * 64;
#pragma unroll
  for (int nt = 0; nt < 4; ++nt) {
    const int col = nc0 + nt * 16 + ql;
    const float bb = bo[col];
#pragma unroll
    for (int mt = 0; mt < 4; ++mt)
#pragma unroll
      for (int r = 0; r < 4; ++r) {
        const int row = mr0 + mt * 16 + quad * 4 + r;
        const size_t ix = (size_t)row * DD + col;
        out[ix] = acc[mt][nt][r] + bb + res[ix];
      }
  }
}

// ---------------------------------------------------------------------------
// Rotary on f16 q,k + cos/sin tables ([B,H,L] fp32)
// ---------------------------------------------------------------------------
__global__ __launch_bounds__(256) void rotary_h(
    _Float16* __restrict__ q, _Float16* __restrict__ k,
    const float* __restrict__ phi, float* __restrict__ cosp,
    float* __restrict__ sinp)
{
  const int idx = blockIdx.x * 256 + threadIdx.x;
  const int d = idx & 31;
  const int h = (idx >> 5) & (HH - 1);
  const int l = (idx >> 9) & (LL - 1);
  const int b = idx >> 20;
  const float ph = phi[(b * LL + l) * HH + h];
  const float c = cosf(ph), s = sinf(ph);
  const size_t base = ((size_t)(b * LL + l) * HH + h) * HDD;
  const float q0 = (float)q[base + d], q1 = (float)q[base + d + 32];
  q[base + d]      = (_Float16)(q0 * c - q1 * s);
  q[base + d + 32] = (_Float16)(q1 * c + q0 * s);
  const float k0v = (float)k[base + d], k1v = (float)k[base + d + 32];
  k[base + d]      = (_Float16)(k0v * c - k1v * s);
  k[base + d + 32] = (_Float16)(k1v * c + k0v * s);
  if (d == 0) {
    cosp[(b * HH + h) * LL + l] = c;
    sinp[(b * HH + h) * LL + l] = s;
  }
}

// ---------------------------------------------------------------------------
// V transpose: [B,L,H,64] -> VT[B,H,64,L].
// ---------------------------------------------------------------------------
__global__ __launch_bounds__(256) void vtrans(
    const _Float16* __restrict__ V, _Float16* __restrict__ VT)
{
  __shared__ _Float16 t[64][72];  // +8 pad
  const int bid = blockIdx.x;
  const int lt = bid & 31, bh = bid >> 5;
  const int b = bh >> 4, h = bh & 15;
  const int l0 = lt * 64;
  const int tid = threadIdx.x;
  {
    const int row = tid >> 2, doff = (tid & 3) * 16;
    const _Float16* src = V + ((size_t)((b * LL + l0 + row) * HH + h)) * HDD + doff;
    *(v8h*)&t[row][doff]     = *(const v8h*)src;
    *(v8h*)&t[row][doff + 8] = *(const v8h*)(src + 8);
  }
  __syncthreads();
  {
    const int d = tid >> 2, lo = (tid & 3) * 16;
    v8h o0, o1;
#pragma unroll
    for (int j = 0; j < 8; ++j) { o0[j] = t[lo + j][d]; o1[j] = t[lo + 8 + j][d]; }
    _Float16* dst = VT + ((size_t)(b * HH + h) * HDD + d) * LL + l0 + lo;
    *(v8h*)dst = o0;
    *(v8h*)(dst + 8) = o1;
  }
}

__device__ __forceinline__ v8h scale8(v8h x) {
  v8h r;
#pragma unroll
  for (int i = 0; i < 8; ++i) r[i] = x[i] * (_Float16)0.125f;
  return r;
}

// ---------------------------------------------------------------------------
// Barrier-free streaming MFMA flash attention, 2-stage software pipeline:
// register tiles for K (S^T A-frags) and VT (PV B-frags) are double-buffered;
// tile t+1's 24 VMEM loads are issued before computing tile t, so L2 latency
// is hidden under MFMA+softmax. __launch_bounds__(256,2): grid gives only
// 2 blocks/CU (2 waves/SIMD), so allow 256 VGPRs for the live buffers.
// ---------------------------------------------------------------------------
__global__ __launch_bounds__(256, 2) void attn_stream(
    const _Float16* __restrict__ Q, const _Float16* __restrict__ K,
    const _Float16* __restrict__ VT, const _Float16* __restrict__ V,
    const float* __restrict__ cosp, const float* __restrict__ sinp,
    const float* __restrict__ am, _Float16* __restrict__ ctx)
{
  __shared__ float4 csA[LL];  // {cos,sin,am,0} per key: 32 KB

  const int tid  = threadIdx.x;
  const int lane = tid & 63;
  const int wave = tid >> 6;
  const int quad = lane >> 4;
  const int ql   = lane & 15;
  const int bid  = blockIdx.x;
  const int bh = bid & 31;        // b*16+h  (XCD swizzle: same (b,h) -> same XCD)
  const int qt = bid >> 5;
  const int h  = bh & 15;
  const int b  = bh >> 4;
  const int q0 = qt * 128 + wave * 32;
  const int csb = (b * HH + h) * LL;

  for (int i = tid; i < LL; i += 256)
    csA[i] = make_float4(cosp[csb + i], sinp[csb + i], am[b * LL + i], 0.f);

  v8h qf[2][2];
  float cq[2], sq[2];
#pragma unroll
  for (int qs = 0; qs < 2; ++qs) {
    const int q = q0 + qs * 16 + ql;
    const _Float16* qp = Q + ((size_t)((b * LL + q) * HH + h)) * HDD + quad * 8;
    qf[qs][0] = scale8(*(const v8h*)qp);
    qf[qs][1] = scale8(*(const v8h*)(qp + 32));
    cq[qs] = cosp[csb + q];
    sq[qs] = sinp[csb + q];
  }

  v4f o[2][4];
#pragma unroll
  for (int qs = 0; qs < 2; ++qs)
#pragma unroll
    for (int nt = 0; nt < 4; ++nt) o[qs][nt] = (v4f){0.f, 0.f, 0.f, 0.f};
  float mrow[2] = {-INFINITY, -INFINITY};
  float lrow[2] = {0.f, 0.f};

  const _Float16* Kb  = K + ((size_t)(b * LL) * HH + h) * HDD;   // row stride 1024
  const _Float16* VTb = VT + (size_t)(b * HH + h) * HDD * LL;

  __syncthreads();  // csA ready (the only barrier)

  auto load_tile = [&](int k0, v8h (&ka)[4][2], v4h (&vf)[4][4]) {
#pragma unroll
    for (int c = 0; c < 4; ++c) {
      const _Float16* kp = Kb + (size_t)(k0 + c * 16 + ql) * 1024 + quad * 8;
      ka[c][0] = *(const v8h*)kp;
      ka[c][1] = *(const v8h*)(kp + 32);
    }
#pragma unroll
    for (int c = 0; c < 4; ++c)
#pragma unroll
      for (int nt = 0; nt < 4; ++nt)
        vf[c][nt] = *(const v4h*)&VTb[(size_t)(nt * 16 + ql) * LL +
                                      k0 + c * 16 + quad * 4];
  };

  auto compute = [&](int k0, const v8h (&ka)[4][2], const v4h (&vf)[4][4]) {
    // S^T for both query sub-tiles
    v4f st2[2][4];
#pragma unroll
    for (int qs = 0; qs < 2; ++qs)
#pragma unroll
      for (int c = 0; c < 4; ++c) {
        v4f z = (v4f){0.f, 0.f, 0.f, 0.f};
        z = __builtin_amdgcn_mfma_f32_16x16x32_f16(ka[c][0], qf[qs][0], z, 0, 0, 0);
        z = __builtin_amdgcn_mfma_f32_16x16x32_f16(ka[c][1], qf[qs][1], z, 0, 0, 0);
        st2[qs][c] = z;
      }
    // mask + scores (csA read once, shared by both qs)
    float s2[2][16];
    float tm[2] = {-INFINITY, -INFINITY};
#pragma unroll
    for (int c = 0; c < 4; ++c)
#pragma unroll
      for (int r = 0; r < 4; ++r) {
        const int kk = c * 16 + quad * 4 + r;
        const float4 cs = csA[k0 + kk];
#pragma unroll
        for (int qs = 0; qs < 2; ++qs) {
          float sc = st2[qs][c][r];
          const bool msk = (cq[qs] * cs.x + sq[qs] * cs.y < -0.7f) &&
                           ((k0 + kk) != (q0 + qs * 16 + ql));
          sc = msk ? -1e9f : sc;
          sc += cs.z;
          s2[qs][c * 4 + r] = sc;
          tm[qs] = fmaxf(tm[qs], sc);
        }
      }
    v4h pf[2][4];
    float alpha_[2];
#pragma unroll
    for (int qs = 0; qs < 2; ++qs) {
      float t = tm[qs];
      t = fmaxf(t, __shfl_xor(t, 16, 64));
      t = fmaxf(t, __shfl_xor(t, 32, 64));
      const float mnew = fmaxf(mrow[qs], t);
      alpha_[qs] = __expf(mrow[qs] - mnew);  // exp(-inf)=0 at init
      mrow[qs] = mnew;
      float ls = 0.f;
#pragma unroll
      for (int i = 0; i < 16; ++i) {
        s2[qs][i] = __expf(s2[qs][i] - mnew);
        ls += s2[qs][i];
      }
      ls += __shfl_xor(ls, 16, 64);
      ls += __shfl_xor(ls, 32, 64);
      lrow[qs] = lrow[qs] * alpha_[qs] + ls;
#pragma unroll
      for (int c = 0; c < 4; ++c) {
        v4h t4;
        t4[0] = (_Float16)s2[qs][c * 4 + 0]; t4[1] = (_Float16)s2[qs][c * 4 + 1];
        t4[2] = (_Float16)s2[qs][c * 4 + 2]; t4[3] = (_Float16)s2[qs][c * 4 + 3];
        pf[qs][c] = t4;
      }
    }
    // rescale O (alpha indexed by query=lane&15 -> remap to O rows quad*4+r)
#pragma unroll
    for (int qs = 0; qs < 2; ++qs) {
      const float a0 = __shfl(alpha_[qs], quad * 4 + 0, 64);
      const float a1 = __shfl(alpha_[qs], quad * 4 + 1, 64);
      const float a2 = __shfl(alpha_[qs], quad * 4 + 2, 64);
      const float a3 = __shfl(alpha_[qs], quad * 4 + 3, 64);
#pragma unroll
      for (int nt = 0; nt < 4; ++nt) {
        o[qs][nt][0] *= a0; o[qs][nt][1] *= a1;
        o[qs][nt][2] *= a2; o[qs][nt][3] *= a3;
      }
    }
    // PV
#pragma unroll
    for (int c = 0; c < 4; ++c)
#pragma unroll
      for (int nt = 0; nt < 4; ++nt) {
        o[0][nt] = __builtin_amdgcn_mfma_f32_16x16x16f16(pf[0][c], vf[c][nt], o[0][nt], 0, 0, 0);
        o[1][nt] = __builtin_amdgcn_mfma_f32_16x16x16f16(pf[1][c], vf[c][nt], o[1][nt], 0, 0, 0);
      }
  };

  v8h kaA[4][2], kaB[4][2];
  v4h vfA[4][4], vfB[4][4];
  load_tile(0, kaA, vfA);
  for (int t = 0; t < 32; t += 2) {
    if (t + 1 < 32) load_tile((t + 1) * 64, kaB, vfB);
    compute(t * 64, kaA, vfA);
    if (t + 2 < 32) load_tile((t + 2) * 64, kaA, vfA);
    if (t + 1 < 32) compute((t + 1) * 64, kaB, vfB);
  }

#pragma unroll
  for (int qs = 0; qs < 2; ++qs) {
    const float inv = 1.f / lrow[qs];
#pragma unroll
    for (int r = 0; r < 4; ++r) {
      const int q = q0 + qs * 16 + quad * 4 + r;
      const float ir = __shfl(inv, quad * 4 + r, 64);
      const float mr = __shfl(mrow[qs], quad * 4 + r, 64);
      const size_t ob = ((size_t)((b * LL + q) * HH + h)) * HDD + ql;
      if (mr <= -1e8f) {  // all-masked fallback (never taken with am=0)
        ctx[ob + 0]  = V[ob + 0];
        ctx[ob + 16] = V[ob + 16];
        ctx[ob + 32] = V[ob + 32];
        ctx[ob + 48] = V[ob + 48];
      } else {
        ctx[ob + 0]  = (_Float16)(o[qs][0][r] * ir);
        ctx[ob + 16] = (_Float16)(o[qs][1][r] * ir);
        ctx[ob + 32] = (_Float16)(o[qs][2][r] * ir);
        ctx[ob + 48] = (_Float16)(o[qs][3][r] * ir);
      }
    }
  }
}

// ---------------------------------------------------------------------------
// LayerNorm over D=1024
// ---------------------------------------------------------------------------
__global__ __launch_bounds__(256) void layernorm(
    const float* __restrict__ x, const float* __restrict__ g,
    const float* __restrict__ bta, float* __restrict__ out)
{
  __shared__ float red[8];
  const int row = blockIdx.x;
  const int tid = threadIdx.x;
  const float* xr = x + (size_t)row * DD;
  float lsum = 0.f, lsq = 0.f;
  float v[4];
#pragma unroll
  for (int i = 0; i < 4; ++i) {
    v[i] = xr[tid + i * 256];
    lsum += v[i];
    lsq += v[i] * v[i];
  }
#pragma unroll
  for (int off = 32; off > 0; off >>= 1) {
    lsum += __shfl_down(lsum, off, 64);
    lsq  += __shfl_down(lsq,  off, 64);
  }
  const int wid = tid >> 6;
  if ((tid & 63) == 0) { red[wid] = lsum; red[wid + 4] = lsq; }
  __syncthreads();
  const float tsum = red[0] + red[1] + red[2] + red[3];
  const float tsq  = red[4] + red[5] + red[6] + red[7];
  const float mean = tsum * (1.f / DD);
  const float var  = tsq * (1.f / DD) - mean * mean;
  const float inv  = rsqrtf(var + 1e-12f);
#pragma unroll
  for (int i = 0; i < 4; ++i) {
    const int c = tid + i * 256;
    out[(size_t)row * DD + c] = (v[i] - mean) * inv * g[c] + bta[c];
  }
}

// ---------------------------------------------------------------------------
extern "C" void kernel_launch(void* const* d_in, const int* in_sizes, int n_in,
                              void* d_out, int out_size, void* d_ws, size_t ws_size,
                              hipStream_t stream)
{
  const float* hs  = (const float*)d_in[0];
  const float* amk = (const float*)d_in[1];
  const float* phi = (const float*)d_in[2];
  const float* Wq  = (const float*)d_in[3];
  const float* bq  = (const float*)d_in[4];
  const float* Wk  = (const float*)d_in[5];
  const float* bk  = (const float*)d_in[6];
  const float* Wv  = (const float*)d_in[7];
  const float* bv  = (const float*)d_in[8];
  const float* Wo  = (const float*)d_in[9];
  const float* bo  = (const float*)d_in[10];
  const float* lng = (const float*)d_in[11];
  const float* lnb = (const float*)d_in[12];
  float* out = (float*)d_out;

  const size_t SZ = (size_t)BB * LL * DD;   // 4 M elements
  _Float16* hsh   = (_Float16*)d_ws;
  _Float16* qh    = hsh + SZ;
  _Float16* kh    = qh + SZ;
  _Float16* vh    = kh + SZ;
  _Float16* ctxh  = vh + SZ;
  _Float16* wqkvh = ctxh + SZ;              // 3 M
  _Float16* woh   = wqkvh + 3 * (size_t)DD * DD;  // 1 M
  _Float16* vth   = woh + (size_t)DD * DD;  // 4 M (V transposed)
  float* xb   = (float*)(vth + SZ);
  float* cosp = xb + SZ;
  float* sinp = cosp + (size_t)BB * HH * LL;

  cvt_all<<<8192, 256, 0, stream>>>(hs, Wq, Wk, Wv, Wo, hsh, wqkvh, woh);
  gemm_qkv<<<dim3(24, 32), 256, 0, stream>>>(hsh, wqkvh, bq, bk, bv, qh, kh, vh);
  rotary_h<<<8192, 256, 0, stream>>>(qh, kh, phi, cosp, sinp);
  vtrans<<<1024, 256, 0, stream>>>(vh, vth);
  attn_stream<<<BB * HH * (LL / 128), 256, 0, stream>>>(qh, kh, vth, vh, cosp,
                                                        sinp, amk, ctxh);
  gemm_o<<<dim3(8, 32), 256, 0, stream>>>(ctxh, woh, bo, hs, xb);
  layernorm<<<BB * LL, 256, 0, stream>>>(xb, lng, lnb, out);
}